// Round 4
// baseline (1229.922 us; speedup 1.0000x reference)
//
#include <hip/hip_runtime.h>
#include <hip/hip_bf16.h>
#include <stdint.h>

// ---------------------------------------------------------------------------
// FusionNet: seq[t,d] = sum_r w[r]*(imu1[t]@A[r,:,d])*(vid1[t]@Bv[r,:,d]) + fb[d]
//            out[t]   = (relu(seq@W1 + b1) @ W2 + b2) / (anthro0*anthro1)
//
// History:
//  R0 (153us): bf16 MFMA, LDS tables+MLP tables (95KB), 512thr, (512,2):
//      VGPR 92 no spill, 1 block/CU, 20% occ. Latency-bound.
//  R1-R3: every attempt to raise occupancy via launch_bounds 2nd-arg or
//      1024-thr blocks collapsed the VGPR budget to 64 -> 55MB spill traffic.
//      Empirical rule: only 512thr+(512,2) allocates sanely here.
//  R4: (a) LDS = ONLY the two 40KB fragment tables (81920B exactly) ->
//      two 512-thr blocks/CU co-resident = 16 waves/CU at the proven
//      (512,2) config. Small MLP tables read from global (L1-resident,
//      quad-uniform broadcast loads). (b) MFMA operand swap: acc becomes
//      [rank=quad*4+reg][token=lane&15] so rank-reduce = 3 in-lane adds +
//      2 shfl_xor per d (was 16 shfl) -- cuts the serial cross-lane chains
//      that kept VALUBusy at 19%. (c) persistent waves: 512 blocks x 8
//      waves x 4 tiles x 16 tokens = 262144 exactly.
// ---------------------------------------------------------------------------

#define NTOK   262144      // B*S = 64*4096
#define FDIM   128
#define RANKN  16
#define FUSED  10
#define WTE    (FUSED*RANKN*FDIM)   // 20480 bf16 elements per weight table

typedef unsigned short u16;
typedef __bf16 bf16x8 __attribute__((ext_vector_type(8)));
typedef float  f32x4  __attribute__((ext_vector_type(4)));

static __device__ __forceinline__ u16 f2bf(float f) {
    union { float f; uint32_t u; } c; c.f = f;
    uint32_t u = c.u + 0x7FFFu + ((c.u >> 16) & 1u);   // RNE
    return (u16)(u >> 16);
}

// ---------------------------------------------------------------------------
// Prep: bf16 weight tables in MFMA fragment order:
//   elem (d, kk, lane=quad*16+r, j) = factor[r, 0, k+1, d],  k = kk*32+quad*8+j
// (same lane map serves as A-operand [m=r][k] or B-operand [n=r][k]).
// Plus: a0/b0 "ones"-row constants [d][16] (f32), b1' = b1 + fb@W1,
// W1q = W1 regrouped [quad][d][32] for f32x4 reads, W2 de-interleaved.
// fusion_weights folded into imu side.
// ---------------------------------------------------------------------------
__global__ void prep_kernel(const float* __restrict__ imf, const float* __restrict__ vif,
                            const float* __restrict__ fw,  const float* __restrict__ fb,
                            const float* __restrict__ W1,  const float* __restrict__ b1,
                            const float* __restrict__ W2,
                            u16* __restrict__ wImu, u16* __restrict__ wVid,
                            float* __restrict__ a0, float* __restrict__ b0,
                            float* __restrict__ b1p, float* __restrict__ W1q,
                            float* __restrict__ w20, float* __restrict__ w21) {
    int idx = blockIdx.x * blockDim.x + threadIdx.x;
    if (idx < FUSED * RANKN * FDIM) {           // 20480
        int k = idx & 127;
        int r = (idx >> 7) & 15;
        int d = idx >> 11;
        int src = r * ((FDIM + 1) * FUSED) + (k + 1) * FUSED + d;  // factor[r,0,k+1,d]
        int kk   = k >> 5;
        int quad = (k >> 3) & 3;
        int j    = k & 7;
        int lane = quad * 16 + r;
        int dst  = ((d * 4 + kk) * 64 + lane) * 8 + j;
        wImu[dst] = f2bf(fw[r] * imf[src]);
        wVid[dst] = f2bf(vif[src]);
    }
    if (idx < RANKN * FUSED) {                  // 160, layout [d][16 ranks]
        int r = idx & 15, d = idx >> 4;
        int src = r * ((FDIM + 1) * FUSED) + d; // factor[r,0,0,d]
        a0[idx] = fw[r] * imf[src];
        b0[idx] = vif[src];
    }
    if (idx < 1280) {                           // W1q[(q*10+d)*32 + w] = W1[d][q*32+w]
        int w = idx & 31;
        int t = idx >> 5;                       // t = q*10 + d
        int d = t % 10;
        int q = t / 10;
        W1q[idx] = W1[d * FDIM + q * 32 + w];
    }
    if (idx < FDIM) {                           // fold fusion_bias through W1
        float acc = b1[idx];
        #pragma unroll
        for (int d = 0; d < FUSED; ++d) acc += fb[d] * W1[d * FDIM + idx];
        b1p[idx] = acc;
        w20[idx] = W2[2 * idx];
        w21[idx] = W2[2 * idx + 1];
    }
}

// ---------------------------------------------------------------------------
// Main: 512 threads = 8 waves. Persistent: each wave owns 64 consecutive
// tokens (4 tiles of 16). LDS = fragment tables only (81920B) -> 2 blocks/CU.
// ---------------------------------------------------------------------------
__launch_bounds__(512, 2)
__global__ void fusion_main(const float* __restrict__ imu, const float* __restrict__ vid,
                            const float* __restrict__ anthro,
                            const u16* __restrict__ wImuG, const u16* __restrict__ wVidG,
                            const float* __restrict__ a0g, const float* __restrict__ b0g,
                            const float* __restrict__ W1qg, const float* __restrict__ b1pg,
                            const float* __restrict__ w20g, const float* __restrict__ w21g,
                            const float* __restrict__ b2g,
                            float* __restrict__ out) {
    extern __shared__ char smem[];
    u16* sFI = (u16*)smem;                // [10][4][64][8] bf16 fragment order
    u16* sFV = sFI + WTE;

    // ---- stage fragment tables to LDS (coalesced uint4 copies) ----
    {
        const uint4* srcI = (const uint4*)wImuG;
        const uint4* srcV = (const uint4*)wVidG;
        uint4* dstI = (uint4*)sFI;
        uint4* dstV = (uint4*)sFV;
        for (int i = threadIdx.x; i < WTE / 8; i += blockDim.x) {
            dstI[i] = srcI[i];
            dstV[i] = srcV[i];
        }
    }
    __syncthreads();

    const int lane = threadIdx.x & 63;
    const int quad = lane >> 4;          // MFMA row-group: ranks quad*4..quad*4+3
    const int r16  = lane & 15;          // token column
    const int wid  = threadIdx.x >> 6;
    const int wgl  = blockIdx.x * 8 + wid;   // global wave id, 0..4095
    const int wbase = wgl * 64;              // 64 consecutive tokens per wave

    // wave's 64 tokens sit inside one batch row-block (4096 % 64 == 0)
    const int bidx = wbase >> 12;
    const float invwh = 1.0f / (anthro[2 * bidx] * anthro[2 * bidx + 1]);
    const float b20 = b2g[0], b21 = b2g[1];

    const bf16x8* fragI = (const bf16x8*)(const void*)sFI;
    const bf16x8* fragV = (const bf16x8*)(const void*)sFV;

    for (int it = 0; it < 4; ++it) {
        const int t0 = wbase + it * 16;

        // ---- token fragments (B-operand after swap): lane holds
        //      T[n=r16][k=quad*8+j]; one modality at a time to cap staging regs
        bf16x8 aI[4], aV[4];
        {
            const float* baseI = imu + (size_t)(t0 + r16) * FDIM + quad * 8;
            #pragma unroll
            for (int kk = 0; kk < 4; ++kk) {
                f32x4 v0 = *(const f32x4*)(baseI + kk * 32);
                f32x4 v1 = *(const f32x4*)(baseI + kk * 32 + 4);
                bf16x8 a;
                #pragma unroll
                for (int j = 0; j < 4; ++j) { a[j] = (__bf16)v0[j]; a[j + 4] = (__bf16)v1[j]; }
                aI[kk] = a;
            }
            const float* baseV = vid + (size_t)(t0 + r16) * FDIM + quad * 8;
            #pragma unroll
            for (int kk = 0; kk < 4; ++kk) {
                f32x4 v0 = *(const f32x4*)(baseV + kk * 32);
                f32x4 v1 = *(const f32x4*)(baseV + kk * 32 + 4);
                bf16x8 a;
                #pragma unroll
                for (int j = 0; j < 4; ++j) { a[j] = (__bf16)v0[j]; a[j + 4] = (__bf16)v1[j]; }
                aV[kk] = a;
            }
        }

        // ---- per d: swapped MFMA -> acc[rank=quad*4+reg][token=r16];
        //      rank-reduce = in-lane sum + 2 cross-quad shfl.
        float seqv[FUSED];
        #pragma unroll
        for (int d = 0; d < FUSED; ++d) {
            f32x4 accU = {0.f, 0.f, 0.f, 0.f};
            f32x4 accV = {0.f, 0.f, 0.f, 0.f};
            #pragma unroll
            for (int kk = 0; kk < 4; ++kk) {
                accU = __builtin_amdgcn_mfma_f32_16x16x32_bf16(fragI[(d * 4 + kk) * 64 + lane], aI[kk], accU, 0, 0, 0);
                accV = __builtin_amdgcn_mfma_f32_16x16x32_bf16(fragV[(d * 4 + kk) * 64 + lane], aV[kk], accV, 0, 0, 0);
            }
            f32x4 a0c = *(const f32x4*)(a0g + d * 16 + quad * 4);
            f32x4 b0c = *(const f32x4*)(b0g + d * 16 + quad * 4);
            float s = 0.f;
            #pragma unroll
            for (int reg = 0; reg < 4; ++reg)
                s += (accU[reg] + a0c[reg]) * (accV[reg] + b0c[reg]);
            s += __shfl_xor(s, 16, 64);
            s += __shfl_xor(s, 32, 64);
            seqv[d] = s;                 // all lanes: seq[token=r16][d]
        }

        // ---- MLP: lane handles token r16, j-columns quad*32..quad*32+31
        //      (4-fold quad redundancy split over j). W1q/b1p/W2 from L1.
        float o0 = 0.f, o1 = 0.f;
        #pragma unroll
        for (int g = 0; g < 8; ++g) {
            const int jb = quad * 32 + g * 4;
            f32x4 h = *(const f32x4*)(b1pg + jb);
            #pragma unroll
            for (int d = 0; d < FUSED; ++d) {
                f32x4 wv = *(const f32x4*)(W1qg + (quad * 10 + d) * 32 + g * 4);
                #pragma unroll
                for (int i = 0; i < 4; ++i) h[i] += seqv[d] * wv[i];
            }
            f32x4 w20v = *(const f32x4*)(w20g + jb);
            f32x4 w21v = *(const f32x4*)(w21g + jb);
            #pragma unroll
            for (int i = 0; i < 4; ++i) {
                float hr = fmaxf(h[i], 0.f);
                o0 += hr * w20v[i];
                o1 += hr * w21v[i];
            }
        }
        o0 += __shfl_xor(o0, 16, 64);
        o0 += __shfl_xor(o0, 32, 64);
        o1 += __shfl_xor(o1, 16, 64);
        o1 += __shfl_xor(o1, 32, 64);

        if (lane < 16) {
            const int t = t0 + r16;
            float2 o = make_float2((o0 + b20) * invwh, (o1 + b21) * invwh);
            *(float2*)(out + 2 * t) = o;
        }
    }
}

// ---------------------------------------------------------------------------
extern "C" void kernel_launch(void* const* d_in, const int* in_sizes, int n_in,
                              void* d_out, int out_size, void* d_ws, size_t ws_size,
                              hipStream_t stream) {
    const float* imu    = (const float*)d_in[0];
    const float* vid    = (const float*)d_in[1];
    const float* anthro = (const float*)d_in[2];
    const float* imf    = (const float*)d_in[3];
    const float* vif    = (const float*)d_in[4];
    const float* fw     = (const float*)d_in[5];
    const float* fb     = (const float*)d_in[6];
    const float* W1     = (const float*)d_in[7];
    const float* b1     = (const float*)d_in[8];
    const float* W2     = (const float*)d_in[9];
    const float* b2     = (const float*)d_in[10];
    float* out = (float*)d_out;

    // workspace: [wImu u16 20480][wVid u16 20480][a0 160][b0 160][b1p 128]
    //            [W1q 1280][w20 128][w21 128]  (floats; all 16B-aligned)
    u16* wImu = (u16*)d_ws;
    u16* wVid = wImu + WTE;
    float* a0  = (float*)(wVid + WTE);
    float* b0  = a0 + 160;
    float* b1p = b0 + 160;
    float* W1q = b1p + 128;
    float* w20 = W1q + 1280;
    float* w21 = w20 + 128;

    prep_kernel<<<80, 256, 0, stream>>>(imf, vif, fw, fb, W1, b1, W2,
                                        wImu, wVid, a0, b0, b1p, W1q, w20, w21);

    const size_t smem = (size_t)(2 * WTE) * sizeof(u16);   // 81920 B exactly
    // 512 blocks x 8 waves x 4 tiles x 16 tokens = 262144 tokens exactly
    fusion_main<<<512, 512, smem, stream>>>(imu, vid, anthro, wImu, wVid,
                                            a0, b0, W1q, b1p, w20, w21, b2, out);
}

// Round 5
// 1216.037 us; speedup vs baseline: 1.0114x; 1.0114x over previous
//
#include <hip/hip_runtime.h>
#include <hip/hip_bf16.h>
#include <stdint.h>

// ---------------------------------------------------------------------------
// FusionNet: seq[t,d] = sum_r w[r]*(imu1[t]@A[r,:,d])*(vid1[t]@Bv[r,:,d]) + fb[d]
//            out[t]   = (relu(seq@W1 + b1) @ W2 + b2) / (anthro0*anthro1)
//
// History:
//  R0 (153us, best): LDS tables+MLP tables (95KB), 512thr, (512,2): VGPR 92,
//      no spill, 1 block/CU, 20% occ. Latency-bound on serial shfl chains.
//  R1-R3: occupancy attempts via launch_bounds/1024thr -> VGPR budget 64 ->
//      spills. Rule: only 512thr+(512,2) allocates sanely.
//  R4: MLP weights from GLOBAL in unrolled loop -> scheduler pipelines 104
//      global loads/tile -> 128 VGPR + 2.8KB/thread scratch (FETCH 1.6GB).
//      Exact-fit 2x80KB LDS did NOT co-reside (per-block overhead) -> occ
//      still 23%. But the swapped-MFMA math was verified correct.
//  R5: R0 structure (everything LDS-resident, no global loads in loop) +
//      swapped MFMA: acc = [rank=quad*4+reg][token=r16] so rank-reduce is
//      3 in-lane adds + 2 shfl (was 16 shfl/d) and seqv is 10 regs (was 40).
//      MLP from LDS, interleaved [g][quad][d][4] layout (quad stride 160B =
//      8 banks -> conflict-free). 512 blocks x 4 tiles/wave amortize staging.
// ---------------------------------------------------------------------------

#define NTOK   262144      // B*S = 64*4096
#define FDIM   128
#define RANKN  16
#define FUSED  10
#define WTE    (FUSED*RANKN*FDIM)   // 20480 bf16 elements per weight table
#define NEXTRA 1984        // f32 extras: a0 160 | b0 160 | W1L 1280 | b1L 128 | w20 128 | w21 128

typedef unsigned short u16;
typedef __bf16 bf16x8 __attribute__((ext_vector_type(8)));
typedef float  f32x4  __attribute__((ext_vector_type(4)));

static __device__ __forceinline__ u16 f2bf(float f) {
    union { float f; uint32_t u; } c; c.f = f;
    uint32_t u = c.u + 0x7FFFu + ((c.u >> 16) & 1u);   // RNE
    return (u16)(u >> 16);
}

// ---------------------------------------------------------------------------
// Prep: bf16 weight tables in MFMA fragment order (works as A or B operand):
//   elem (d, kk, lane=quad*16+r, j) = factor[r, 0, k+1, d],  k = kk*32+quad*8+j
// Extras (f32, contiguous block):
//   a0/b0 [d][16]: "ones"-row constants (rank r at slot r)
//   W1L  [(g*4+quad)*10+d][4]: W1[d][quad*32+g*4+i]   (MLP j-split layout)
//   b1L  [(g*4+quad)][4]:   b1'[j],  b1' = b1 + fb@W1
//   w20/w21 [(g*4+quad)][4]: W2[j][0], W2[j][1]
// fusion_weights folded into imu side.
// ---------------------------------------------------------------------------
__global__ void prep_kernel(const float* __restrict__ imf, const float* __restrict__ vif,
                            const float* __restrict__ fw,  const float* __restrict__ fb,
                            const float* __restrict__ W1,  const float* __restrict__ b1,
                            const float* __restrict__ W2,
                            u16* __restrict__ wImu, u16* __restrict__ wVid,
                            float* __restrict__ extra) {
    int idx = blockIdx.x * blockDim.x + threadIdx.x;
    float* a0  = extra;
    float* b0  = extra + 160;
    float* W1L = extra + 320;
    float* b1L = extra + 1600;
    float* w20 = extra + 1728;
    float* w21 = extra + 1856;

    if (idx < FUSED * RANKN * FDIM) {           // 20480
        int k = idx & 127;
        int r = (idx >> 7) & 15;
        int d = idx >> 11;
        int src = r * ((FDIM + 1) * FUSED) + (k + 1) * FUSED + d;  // factor[r,0,k+1,d]
        int kk   = k >> 5;
        int quad = (k >> 3) & 3;
        int j    = k & 7;
        int lane = quad * 16 + r;
        int dst  = ((d * 4 + kk) * 64 + lane) * 8 + j;
        wImu[dst] = f2bf(fw[r] * imf[src]);
        wVid[dst] = f2bf(vif[src]);
    }
    if (idx < RANKN * FUSED) {                  // 160, layout [d][16 ranks]
        int r = idx & 15, d = idx >> 4;
        int src = r * ((FDIM + 1) * FUSED) + d; // factor[r,0,0,d]
        a0[idx] = fw[r] * imf[src];
        b0[idx] = vif[src];
    }
    if (idx < 1280) {                           // W1L[(g*4+q)*10+d][i] = W1[d][q*32+g*4+i]
        int i = idx & 3;
        int t = idx >> 2;                       // 0..319
        int d = t % 10;
        int gq = t / 10;                        // 0..31
        int g = gq >> 2, q = gq & 3;
        int j = q * 32 + g * 4 + i;
        W1L[idx] = W1[d * FDIM + j];
    }
    if (idx < FDIM) {                           // b1L / w20 / w21 in gq layout
        int i = idx & 3;
        int gq = idx >> 2;
        int g = gq >> 2, q = gq & 3;
        int j = q * 32 + g * 4 + i;
        float acc = b1[j];
        #pragma unroll
        for (int d = 0; d < FUSED; ++d) acc += fb[d] * W1[d * FDIM + j];
        b1L[idx] = acc;
        w20[idx] = W2[2 * j];
        w21[idx] = W2[2 * j + 1];
    }
}

// ---------------------------------------------------------------------------
// Main: 512 threads = 8 waves, (512,2) -> 128-VGPR budget (proven no-spill
// config). Each wave owns 64 consecutive tokens (4 tiles of 16). All loop
// data LDS-resident; only token loads + output stores touch global.
// ---------------------------------------------------------------------------
__launch_bounds__(512, 2)
__global__ void fusion_main(const float* __restrict__ imu, const float* __restrict__ vid,
                            const float* __restrict__ anthro,
                            const u16* __restrict__ wImuG, const u16* __restrict__ wVidG,
                            const float* __restrict__ extraG,
                            const float* __restrict__ b2g,
                            float* __restrict__ out) {
    extern __shared__ char smem[];
    u16* sFI = (u16*)smem;                // [10][4][64][8] bf16 fragment order
    u16* sFV = sFI + WTE;
    float* sX   = (float*)(sFV + WTE);    // extras block (1984 f32)
    float* sA0  = sX;                     // [10][16]
    float* sB0  = sX + 160;
    float* sW1L = sX + 320;               // [32 gq][10][4]
    float* sB1L = sX + 1600;              // [32 gq][4]
    float* sW20 = sX + 1728;              // [32 gq][4]
    float* sW21 = sX + 1856;              // [32 gq][4]

    // ---- stage to LDS (coalesced uint4 copies) ----
    {
        const uint4* srcI = (const uint4*)wImuG;
        const uint4* srcV = (const uint4*)wVidG;
        const uint4* srcX = (const uint4*)extraG;
        uint4* dstI = (uint4*)sFI;
        uint4* dstV = (uint4*)sFV;
        uint4* dstX = (uint4*)sX;
        for (int i = threadIdx.x; i < WTE / 8; i += blockDim.x) {  // 2560
            dstI[i] = srcI[i];
            dstV[i] = srcV[i];
        }
        for (int i = threadIdx.x; i < NEXTRA / 4; i += blockDim.x) // 496
            dstX[i] = srcX[i];
    }
    __syncthreads();

    const int lane = threadIdx.x & 63;
    const int quad = lane >> 4;          // acc rows: ranks quad*4..quad*4+3
    const int r16  = lane & 15;          // token column
    const int wid  = threadIdx.x >> 6;
    const int wgl  = blockIdx.x * 8 + wid;   // 0..4095
    const int wbase = wgl * 64;              // 64 consecutive tokens per wave

    const int bidx = wbase >> 12;            // S=4096, 64|4096 -> uniform
    const float invwh = 1.0f / (anthro[2 * bidx] * anthro[2 * bidx + 1]);
    const float b20 = b2g[0], b21 = b2g[1];

    const bf16x8* fragI = (const bf16x8*)(const void*)sFI;
    const bf16x8* fragV = (const bf16x8*)(const void*)sFV;

    for (int it = 0; it < 4; ++it) {
        const int t0 = wbase + it * 16;

        // ---- token fragments (B operand): lane holds T[n=r16][k=quad*8+j]
        bf16x8 aI[4], aV[4];
        {
            const float* baseI = imu + (size_t)(t0 + r16) * FDIM + quad * 8;
            const float* baseV = vid + (size_t)(t0 + r16) * FDIM + quad * 8;
            #pragma unroll
            for (int kk = 0; kk < 4; ++kk) {
                f32x4 v0 = *(const f32x4*)(baseI + kk * 32);
                f32x4 v1 = *(const f32x4*)(baseI + kk * 32 + 4);
                f32x4 w0 = *(const f32x4*)(baseV + kk * 32);
                f32x4 w1 = *(const f32x4*)(baseV + kk * 32 + 4);
                bf16x8 a, b;
                #pragma unroll
                for (int j = 0; j < 4; ++j) {
                    a[j] = (__bf16)v0[j]; a[j + 4] = (__bf16)v1[j];
                    b[j] = (__bf16)w0[j]; b[j + 4] = (__bf16)w1[j];
                }
                aI[kk] = a;
                aV[kk] = b;
            }
        }

        // ---- per d: swapped MFMA -> acc[rank=quad*4+reg][token=r16];
        //      rank-reduce = 4 in-lane products + 2 cross-quad shfl.
        float seqv[FUSED];
        #pragma unroll
        for (int d = 0; d < FUSED; ++d) {
            f32x4 accU = {0.f, 0.f, 0.f, 0.f};
            f32x4 accV = {0.f, 0.f, 0.f, 0.f};
            #pragma unroll
            for (int kk = 0; kk < 4; ++kk) {
                accU = __builtin_amdgcn_mfma_f32_16x16x32_bf16(fragI[(d * 4 + kk) * 64 + lane], aI[kk], accU, 0, 0, 0);
                accV = __builtin_amdgcn_mfma_f32_16x16x32_bf16(fragV[(d * 4 + kk) * 64 + lane], aV[kk], accV, 0, 0, 0);
            }
            f32x4 a0c = *(const f32x4*)(sA0 + d * 16 + quad * 4);   // banks 0-15, cf-free
            f32x4 b0c = *(const f32x4*)(sB0 + d * 16 + quad * 4);
            float s = 0.f;
            #pragma unroll
            for (int reg = 0; reg < 4; ++reg)
                s += (accU[reg] + a0c[reg]) * (accV[reg] + b0c[reg]);
            s += __shfl_xor(s, 16, 64);
            s += __shfl_xor(s, 32, 64);
            seqv[d] = s;                 // every lane: seq[token=r16][d]
        }

        // ---- MLP from LDS: lane = token r16, j-columns quad*32+g*4..+3
        //      W1L quad-stride = 160B = 8 banks -> conflict-free broadcasts.
        float o0 = 0.f, o1 = 0.f;
        #pragma unroll
        for (int g = 0; g < 8; ++g) {
            const int gq = g * 4 + quad;
            f32x4 h = *(const f32x4*)(sB1L + gq * 4);
            #pragma unroll
            for (int d = 0; d < FUSED; ++d) {
                f32x4 wv = *(const f32x4*)(sW1L + (gq * 10 + d) * 4);
                #pragma unroll
                for (int i = 0; i < 4; ++i) h[i] += seqv[d] * wv[i];
            }
            f32x4 w20v = *(const f32x4*)(sW20 + gq * 4);
            f32x4 w21v = *(const f32x4*)(sW21 + gq * 4);
            #pragma unroll
            for (int i = 0; i < 4; ++i) {
                float hr = fmaxf(h[i], 0.f);
                o0 += hr * w20v[i];
                o1 += hr * w21v[i];
            }
        }
        o0 += __shfl_xor(o0, 16, 64);
        o0 += __shfl_xor(o0, 32, 64);
        o1 += __shfl_xor(o1, 16, 64);
        o1 += __shfl_xor(o1, 32, 64);

        if (lane < 16) {
            const int t = t0 + r16;
            float2 o = make_float2((o0 + b20) * invwh, (o1 + b21) * invwh);
            *(float2*)(out + 2 * t) = o;
        }
    }
}

// ---------------------------------------------------------------------------
extern "C" void kernel_launch(void* const* d_in, const int* in_sizes, int n_in,
                              void* d_out, int out_size, void* d_ws, size_t ws_size,
                              hipStream_t stream) {
    const float* imu    = (const float*)d_in[0];
    const float* vid    = (const float*)d_in[1];
    const float* anthro = (const float*)d_in[2];
    const float* imf    = (const float*)d_in[3];
    const float* vif    = (const float*)d_in[4];
    const float* fw     = (const float*)d_in[5];
    const float* fb     = (const float*)d_in[6];
    const float* W1     = (const float*)d_in[7];
    const float* b1     = (const float*)d_in[8];
    const float* W2     = (const float*)d_in[9];
    const float* b2     = (const float*)d_in[10];
    float* out = (float*)d_out;

    // workspace: [wImu u16 20480][wVid u16 20480][extras f32 1984]
    u16* wImu = (u16*)d_ws;
    u16* wVid = wImu + WTE;
    float* extra = (float*)(wVid + WTE);

    prep_kernel<<<80, 256, 0, stream>>>(imf, vif, fw, fb, W1, b1, W2,
                                        wImu, wVid, extra);

    const size_t smem = (size_t)(2 * WTE) * sizeof(u16)
                      + (size_t)NEXTRA * sizeof(float);    // 89856 B
    // 512 blocks x 8 waves x 4 tiles x 16 tokens = 262144 tokens exactly
    fusion_main<<<512, 512, smem, stream>>>(imu, vid, anthro, wImu, wVid,
                                            extra, b2, out);
}

// Round 6
// 318.792 us; speedup vs baseline: 3.8581x; 3.8145x over previous
//
#include <hip/hip_runtime.h>
#include <hip/hip_bf16.h>
#include <stdint.h>

// ---------------------------------------------------------------------------
// FusionNet: seq[t,d] = sum_r w[r]*(imu1[t]@A[r,:,d])*(vid1[t]@Bv[r,:,d]) + fb[d]
//            out[t]   = (relu(seq@W1 + b1) @ W2 + b2) / (anthro0*anthro1)
//
// History:
//  R0 (153us, best): LDS tables+MLP (95KB), 2048 blk x 512thr, (512,2),
//      one 16-token tile/wave. VGPR 92, no spill, 20% occ. Latency-bound
//      on serial shfl chains (160 shfl_xor/tile).
//  R1-R3: occupancy via launch_bounds/1024thr -> VGPR budget 64 -> spills.
//      Rule: only 512thr+(512,2) allocates sanely.
//  R4-R5: 4-tile persistent loop -> compiler fully unrolls/pipelines ->
//      4x staging state live -> 128 VGPR + 2.8KB/thread scratch (FETCH
//      1.6GB, 1030us). Lesson: NO multi-tile loops; one tile per wave.
//  R6: R0 grid/structure exactly + swapped MFMA (verified in R4/R5):
//      acc = [rank=quad*4+reg][token=r16] -> rank-reduce = 4 in-lane
//      products + 2 shfl (was 16 shfl per d), seqv 10 regs (was 40),
//      uniform store (lane<16, contiguous 128B). MLP from LDS in
//      conflict-free [gq][d][4] layout.
// ---------------------------------------------------------------------------

#define NTOK   262144      // B*S = 64*4096
#define FDIM   128
#define RANKN  16
#define FUSED  10
#define WTE    (FUSED*RANKN*FDIM)   // 20480 bf16 elements per weight table
#define NEXTRA 1984        // f32 extras: a0 160 | b0 160 | W1L 1280 | b1L 128 | w20 128 | w21 128

typedef unsigned short u16;
typedef __bf16 bf16x8 __attribute__((ext_vector_type(8)));
typedef float  f32x4  __attribute__((ext_vector_type(4)));

static __device__ __forceinline__ u16 f2bf(float f) {
    union { float f; uint32_t u; } c; c.f = f;
    uint32_t u = c.u + 0x7FFFu + ((c.u >> 16) & 1u);   // RNE
    return (u16)(u >> 16);
}

// ---------------------------------------------------------------------------
// Prep: bf16 weight tables in MFMA fragment order (works as A or B operand):
//   elem (d, kk, lane=quad*16+r, j) = factor[r, 0, k+1, d],  k = kk*32+quad*8+j
// Extras (f32, contiguous block):
//   a0/b0 [d][16]: "ones"-row constants (rank r at slot r)
//   W1L  [(g*4+quad)*10+d][4]: W1[d][quad*32+g*4+i]   (MLP j-split layout)
//   b1L  [(g*4+quad)][4]:   b1'[j],  b1' = b1 + fb@W1
//   w20/w21 [(g*4+quad)][4]: W2[j][0], W2[j][1]
// fusion_weights folded into imu side.
// ---------------------------------------------------------------------------
__global__ void prep_kernel(const float* __restrict__ imf, const float* __restrict__ vif,
                            const float* __restrict__ fw,  const float* __restrict__ fb,
                            const float* __restrict__ W1,  const float* __restrict__ b1,
                            const float* __restrict__ W2,
                            u16* __restrict__ wImu, u16* __restrict__ wVid,
                            float* __restrict__ extra) {
    int idx = blockIdx.x * blockDim.x + threadIdx.x;
    float* a0  = extra;
    float* b0  = extra + 160;
    float* W1L = extra + 320;
    float* b1L = extra + 1600;
    float* w20 = extra + 1728;
    float* w21 = extra + 1856;

    if (idx < FUSED * RANKN * FDIM) {           // 20480
        int k = idx & 127;
        int r = (idx >> 7) & 15;
        int d = idx >> 11;
        int src = r * ((FDIM + 1) * FUSED) + (k + 1) * FUSED + d;  // factor[r,0,k+1,d]
        int kk   = k >> 5;
        int quad = (k >> 3) & 3;
        int j    = k & 7;
        int lane = quad * 16 + r;
        int dst  = ((d * 4 + kk) * 64 + lane) * 8 + j;
        wImu[dst] = f2bf(fw[r] * imf[src]);
        wVid[dst] = f2bf(vif[src]);
    }
    if (idx < RANKN * FUSED) {                  // 160, layout [d][16 ranks]
        int r = idx & 15, d = idx >> 4;
        int src = r * ((FDIM + 1) * FUSED) + d; // factor[r,0,0,d]
        a0[idx] = fw[r] * imf[src];
        b0[idx] = vif[src];
    }
    if (idx < 1280) {                           // W1L[(g*4+q)*10+d][i] = W1[d][q*32+g*4+i]
        int i = idx & 3;
        int t = idx >> 2;                       // 0..319
        int d = t % 10;
        int gq = t / 10;                        // 0..31
        int g = gq >> 2, q = gq & 3;
        int j = q * 32 + g * 4 + i;
        W1L[idx] = W1[d * FDIM + j];
    }
    if (idx < FDIM) {                           // b1L / w20 / w21 in gq layout
        int i = idx & 3;
        int gq = idx >> 2;
        int g = gq >> 2, q = gq & 3;
        int j = q * 32 + g * 4 + i;
        float acc = b1[j];
        #pragma unroll
        for (int d = 0; d < FUSED; ++d) acc += fb[d] * W1[d * FDIM + j];
        b1L[idx] = acc;
        w20[idx] = W2[2 * j];
        w21[idx] = W2[2 * j + 1];
    }
}

// ---------------------------------------------------------------------------
// Main: 512 threads = 8 waves, (512,2) -> 128-VGPR budget (proven no-spill).
// ONE 16-token tile per wave (no persistent loop -- R4/R5 lesson).
// All loop data LDS-resident; only token loads + output stores touch global.
// ---------------------------------------------------------------------------
__launch_bounds__(512, 2)
__global__ void fusion_main(const float* __restrict__ imu, const float* __restrict__ vid,
                            const float* __restrict__ anthro,
                            const u16* __restrict__ wImuG, const u16* __restrict__ wVidG,
                            const float* __restrict__ extraG,
                            const float* __restrict__ b2g,
                            float* __restrict__ out) {
    extern __shared__ char smem[];
    u16* sFI = (u16*)smem;                // [10][4][64][8] bf16 fragment order
    u16* sFV = sFI + WTE;
    float* sX   = (float*)(sFV + WTE);    // extras block (1984 f32)
    float* sA0  = sX;                     // [10][16]
    float* sB0  = sX + 160;
    float* sW1L = sX + 320;               // [32 gq][10][4]
    float* sB1L = sX + 1600;              // [32 gq][4]
    float* sW20 = sX + 1728;              // [32 gq][4]
    float* sW21 = sX + 1856;              // [32 gq][4]

    // ---- stage to LDS (coalesced uint4 copies) ----
    {
        const uint4* srcI = (const uint4*)wImuG;
        const uint4* srcV = (const uint4*)wVidG;
        const uint4* srcX = (const uint4*)extraG;
        uint4* dstI = (uint4*)sFI;
        uint4* dstV = (uint4*)sFV;
        uint4* dstX = (uint4*)sX;
        for (int i = threadIdx.x; i < WTE / 8; i += blockDim.x) {  // 2560
            dstI[i] = srcI[i];
            dstV[i] = srcV[i];
        }
        for (int i = threadIdx.x; i < NEXTRA / 4; i += blockDim.x) // 496
            dstX[i] = srcX[i];
    }

    const int lane = threadIdx.x & 63;
    const int quad = lane >> 4;          // acc rows: ranks quad*4..quad*4+3
    const int r16  = lane & 15;          // token column
    const int wid  = threadIdx.x >> 6;
    const int t0   = (blockIdx.x * 8 + wid) * 16;   // one tile per wave

    const int bidx = t0 >> 12;           // S = 4096
    const float invwh = 1.0f / (anthro[2 * bidx] * anthro[2 * bidx + 1]);
    const float b20 = b2g[0], b21 = b2g[1];

    // ---- token fragments (B operand): lane holds T[n=r16][k=quad*8+j]
    //      (global loads issue before the barrier; latency overlaps staging)
    bf16x8 aI[4], aV[4];
    {
        const float* baseI = imu + (size_t)(t0 + r16) * FDIM + quad * 8;
        const float* baseV = vid + (size_t)(t0 + r16) * FDIM + quad * 8;
        #pragma unroll
        for (int kk = 0; kk < 4; ++kk) {
            f32x4 v0 = *(const f32x4*)(baseI + kk * 32);
            f32x4 v1 = *(const f32x4*)(baseI + kk * 32 + 4);
            f32x4 w0 = *(const f32x4*)(baseV + kk * 32);
            f32x4 w1 = *(const f32x4*)(baseV + kk * 32 + 4);
            bf16x8 a, b;
            #pragma unroll
            for (int j = 0; j < 4; ++j) {
                a[j] = (__bf16)v0[j]; a[j + 4] = (__bf16)v1[j];
                b[j] = (__bf16)w0[j]; b[j + 4] = (__bf16)w1[j];
            }
            aI[kk] = a;
            aV[kk] = b;
        }
    }
    __syncthreads();

    const bf16x8* fragI = (const bf16x8*)(const void*)sFI;
    const bf16x8* fragV = (const bf16x8*)(const void*)sFV;

    // ---- per d: swapped MFMA -> acc[rank=quad*4+reg][token=r16];
    //      rank-reduce = 4 in-lane products + 2 cross-quad shfl.
    float seqv[FUSED];
    #pragma unroll
    for (int d = 0; d < FUSED; ++d) {
        f32x4 accU = {0.f, 0.f, 0.f, 0.f};
        f32x4 accV = {0.f, 0.f, 0.f, 0.f};
        #pragma unroll
        for (int kk = 0; kk < 4; ++kk) {
            accU = __builtin_amdgcn_mfma_f32_16x16x32_bf16(fragI[(d * 4 + kk) * 64 + lane], aI[kk], accU, 0, 0, 0);
            accV = __builtin_amdgcn_mfma_f32_16x16x32_bf16(fragV[(d * 4 + kk) * 64 + lane], aV[kk], accV, 0, 0, 0);
        }
        f32x4 a0c = *(const f32x4*)(sA0 + d * 16 + quad * 4);   // banks 0-15, cf-free
        f32x4 b0c = *(const f32x4*)(sB0 + d * 16 + quad * 4);
        float s = 0.f;
        #pragma unroll
        for (int reg = 0; reg < 4; ++reg)
            s += (accU[reg] + a0c[reg]) * (accV[reg] + b0c[reg]);
        s += __shfl_xor(s, 16, 64);
        s += __shfl_xor(s, 32, 64);
        seqv[d] = s;                 // every lane: seq[token=r16][d]
    }

    // ---- MLP from LDS: lane = token r16, j-columns quad*32+g*4..+3
    //      W1L quad-stride = 160B = 8 banks -> conflict-free broadcasts.
    float o0 = 0.f, o1 = 0.f;
    #pragma unroll
    for (int g = 0; g < 8; ++g) {
        const int gq = g * 4 + quad;
        f32x4 h = *(const f32x4*)(sB1L + gq * 4);
        #pragma unroll
        for (int d = 0; d < FUSED; ++d) {
            f32x4 wv = *(const f32x4*)(sW1L + (gq * 10 + d) * 4);
            #pragma unroll
            for (int i = 0; i < 4; ++i) h[i] += seqv[d] * wv[i];
        }
        f32x4 w20v = *(const f32x4*)(sW20 + gq * 4);
        f32x4 w21v = *(const f32x4*)(sW21 + gq * 4);
        #pragma unroll
        for (int i = 0; i < 4; ++i) {
            float hr = fmaxf(h[i], 0.f);
            o0 += hr * w20v[i];
            o1 += hr * w21v[i];
        }
    }
    o0 += __shfl_xor(o0, 16, 64);
    o0 += __shfl_xor(o0, 32, 64);
    o1 += __shfl_xor(o1, 16, 64);
    o1 += __shfl_xor(o1, 32, 64);

    if (lane < 16) {
        const int t = t0 + r16;
        float2 o = make_float2((o0 + b20) * invwh, (o1 + b21) * invwh);
        *(float2*)(out + 2 * t) = o;
    }
}

// ---------------------------------------------------------------------------
extern "C" void kernel_launch(void* const* d_in, const int* in_sizes, int n_in,
                              void* d_out, int out_size, void* d_ws, size_t ws_size,
                              hipStream_t stream) {
    const float* imu    = (const float*)d_in[0];
    const float* vid    = (const float*)d_in[1];
    const float* anthro = (const float*)d_in[2];
    const float* imf    = (const float*)d_in[3];
    const float* vif    = (const float*)d_in[4];
    const float* fw     = (const float*)d_in[5];
    const float* fb     = (const float*)d_in[6];
    const float* W1     = (const float*)d_in[7];
    const float* b1     = (const float*)d_in[8];
    const float* W2     = (const float*)d_in[9];
    const float* b2     = (const float*)d_in[10];
    float* out = (float*)d_out;

    // workspace: [wImu u16 20480][wVid u16 20480][extras f32 1984]
    u16* wImu = (u16*)d_ws;
    u16* wVid = wImu + WTE;
    float* extra = (float*)(wVid + WTE);

    prep_kernel<<<80, 256, 0, stream>>>(imf, vif, fw, fb, W1, b1, W2,
                                        wImu, wVid, extra);

    const size_t smem = (size_t)(2 * WTE) * sizeof(u16)
                      + (size_t)NEXTRA * sizeof(float);    // 89856 B
    // 2048 blocks x 8 waves x 16 tokens = 262144 tokens exactly
    fusion_main<<<2048, 512, smem, stream>>>(imu, vid, anthro, wImu, wVid,
                                             extra, b2, out);
}